// Round 3
// baseline (55.203 us; speedup 1.0000x reference)
//
#include <hip/hip_runtime.h>

// Box filter 1024x1024 constant kernel, reflect pad (pl=pt=511, pr=pb=512).
// K1: per-8-row blocks do horizontal prefix-window sums -> T, and accumulate
//     8-row column sums in registers -> B8 (bases for the vertical pass).
// K2: per (ch, 64-row band, 64-col strip) blocks scan the two 64-row T
//     windows each output band needs, with bases summed from B8 in-wave.

static constexpr float KC = 2.5652997311834374e-21f;
#define IMG (1024 * 1024)

__device__ __forceinline__ float hwindow(const float* S, int o) {
    float r = 0.f;
    if (o <= 510) r += S[512 - o] - S[1];                 // left mirror
    const int b0 = o > 511 ? o - 511 : 0;                 // main
    const int b1 = o + 513 < 1024 ? o + 513 : 1024;
    r += S[b1] - S[b0];
    if (o >= 512) r += S[1023] - S[1534 - o];             // right mirror
    return r;
}

// ---- K1: horizontal pass + 8-row column sums. grid 768 x 512 threads ------
__global__ __launch_bounds__(512) void hpass8_kernel(const float* __restrict__ x,
                                                     float* __restrict__ T,
                                                     float* __restrict__ B8) {
    __shared__ float S[2][1025];
    __shared__ float wtot[2][4];
    __shared__ float PS[1024];
    const int tid = threadIdx.x;
    const int sub = tid >> 8, st = tid & 255;   // two 256-thread halves
    const int lane = tid & 63, wv = st >> 6;    // wave-in-half 0..3
    float cs0 = 0.f, cs1 = 0.f, cs2 = 0.f, cs3 = 0.f;
    const int row0 = blockIdx.x * 8 + sub * 4;
    float* Ss = S[sub];

    for (int it = 0; it < 4; ++it) {
        const size_t rb = (size_t)(row0 + it) * 1024;
        const float4 v = reinterpret_cast<const float4*>(x + rb)[st];
        const float p0 = v.x, p1 = p0 + v.y, p2 = p1 + v.z, p3 = p2 + v.w;
        float inc = p3;
        #pragma unroll
        for (int off = 1; off < 64; off <<= 1) {
            float n = __shfl_up(inc, off);
            if (lane >= off) inc += n;
        }
        if (lane == 63) wtot[sub][wv] = inc;
        __syncthreads();
        float woff = 0.f;
        for (int w = 0; w < wv; ++w) woff += wtot[sub][w];
        const float excl = woff + inc - p3;
        Ss[4 * st + 0] = excl;
        Ss[4 * st + 1] = excl + p0;
        Ss[4 * st + 2] = excl + p1;
        Ss[4 * st + 3] = excl + p2;
        if (st == 255) Ss[1024] = excl + p3;
        __syncthreads();
        float4 o;
        const int ox = 4 * st;
        o.x = hwindow(Ss, ox + 0);
        o.y = hwindow(Ss, ox + 1);
        o.z = hwindow(Ss, ox + 2);
        o.w = hwindow(Ss, ox + 3);
        reinterpret_cast<float4*>(T + rb)[st] = o;
        cs0 += o.x; cs1 += o.y; cs2 += o.z; cs3 += o.w;
    }
    if (sub == 0) {
        PS[4 * st + 0] = cs0; PS[4 * st + 1] = cs1;
        PS[4 * st + 2] = cs2; PS[4 * st + 3] = cs3;
    }
    __syncthreads();
    if (sub == 1) {
        float4 b;
        b.x = PS[4 * st + 0] + cs0;
        b.y = PS[4 * st + 1] + cs1;
        b.z = PS[4 * st + 2] + cs2;
        b.w = PS[4 * st + 3] + cs3;
        reinterpret_cast<float4*>(B8 + (size_t)blockIdx.x * 1024)[st] = b;
    }
}

// ---- K2: vertical windows. grid 1536 = ch(6) x band(16) x strip(16) -------
// 4 waves: (w = window 0/1, h = row-half 0/1). h=0 scans rows 0..31 with the
// true base (sum of B8 rows); h=1 scans rows 32..63 base-free; output adds
// the h=0 total (W[w][31][c]) as correction for r>=32.
__global__ __launch_bounds__(256) void vwin_kernel(const float* __restrict__ T,
                                                   const float* __restrict__ B8,
                                                   float* __restrict__ out) {
    __shared__ float W[2][64][64];
    __shared__ float PT[64];
    const int t = threadIdx.x;
    const int b = blockIdx.x;
    const int strip = b & 15, band = (b >> 4) & 15, ch = b >> 8;
    const int O = band * 64, C = strip * 64;
    const float* Tc = T + (size_t)ch * IMG;
    const float* Bc = B8 + (size_t)ch * 128 * 1024;
    const int c = t & 63, grp = t >> 6;
    const int w = grp & 1, h = grp >> 1;
    const int gc = C + c;

    int s, pre, K;
    if (band <= 7) {
        if (w == 0) { s = 448 - O; pre = 0; K = 56 - 8 * band; }   // P[449-O+i]
        else        { s = O + 512; pre = 0; K = 64 + 8 * band; }   // P[O+513+i]
    } else {
        if (w == 0) { s = O - 512;  pre = 0; K = 8 * band - 64; }  // P[O-511+i]
        else        { s = 1464 - O; pre = 6; K = 183 - 8 * band; } // P[1471-O+i]
    }

    if (h == 0) {
        float run = 0.f;
        for (int k = 0; k < K; ++k) run += Bc[(size_t)k * 1024 + gc];
        const float* p = Tc + (size_t)s * 1024 + gc;
        for (int j = 0; j < pre; ++j) run += p[(size_t)j * 1024];
        p += (size_t)pre * 1024;
        #pragma unroll 8
        for (int i = 0; i < 32; ++i) { run += p[(size_t)i * 1024]; W[w][i][c] = run; }
    } else {
        float run = 0.f;
        const float* p = Tc + (size_t)(s + pre + 32) * 1024 + gc;
        #pragma unroll 8
        for (int i = 0; i < 32; ++i) { run += p[(size_t)i * 1024]; W[w][32 + i][c] = run; }
        if (w == 1) {
            float pt = 0.f;
            #pragma unroll 8
            for (int k = 0; k < 128; ++k) pt += Bc[(size_t)k * 1024 + gc];
            PT[c] = pt;
        }
    }
    __syncthreads();

    const int q = grp;                        // 4 quarters x 16 rows
    float* ob = out + (size_t)ch * IMG + (size_t)O * 1024 + C;
    const float c1 = W[0][31][c], c2 = W[1][31][c];
    if (band <= 7) {
        const float P1 = Tc[gc];              // P[1] = T row 0
        for (int j = 0; j < 16; ++j) {
            const int ly = q * 16 + j;
            const int r1 = 63 - ly;
            float w1 = W[0][r1][c]; if (r1 >= 32) w1 += c1;
            float w2 = W[1][ly][c]; if (ly >= 32) w2 += c2;
            ob[(size_t)ly * 1024 + c] = KC * (w2 + (w1 - P1));
        }
    } else {
        const float pt = PT[c];
        const float Pm = pt - Tc[(size_t)1023 * 1024 + gc];  // P[1023]
        for (int j = 0; j < 16; ++j) {
            const int ly = q * 16 + j;
            float w1 = W[0][ly][c]; if (ly >= 32) w1 += c1;
            const int r2 = 63 - ly;
            float w2 = W[1][r2][c]; if (r2 >= 32) w2 += c2;
            ob[(size_t)ly * 1024 + c] = KC * ((pt - w1) + (Pm - w2));
        }
    }
}

extern "C" void kernel_launch(void* const* d_in, const int* in_sizes, int n_in,
                              void* d_out, int out_size, void* d_ws, size_t ws_size,
                              hipStream_t stream) {
    const float* x = (const float*)d_in[2];
    float* out = (float*)d_out;
    float* T = (float*)d_ws;                       // 6*IMG floats
    float* B8 = T + (size_t)6 * IMG;               // 768*1024 floats
    hpass8_kernel<<<768, 512, 0, stream>>>(x, T, B8);
    vwin_kernel<<<1536, 256, 0, stream>>>(T, B8, out);
}